// Round 4
// baseline (176.001 us; speedup 1.0000x reference)
//
#include <hip/hip_runtime.h>

#define N_NODES 50000
#define N_EDGES 800000
#define HEADS 8
#define NEG_SLOPE 0.2f
#define EPS 1e-16f
#define NBUCK 782            // ceil(50000/64) buckets of 64 dst nodes
#define BNODES 64
#define BCAP 1312            // bucket capacity (load ~Poisson(1023); +9 sigma)
#define GEMMB 782            // gemm blocks (64 rows each)
#define BINB 250             // bin blocks
#define EPB 3200             // 800000 / 250 edges per bin block
#define LOG2E 1.4426950408889634f

// bf16x2 pack/unpack (RNE), exact unpack
__device__ inline unsigned int f2_to_bf2(float a, float b) {
    unsigned int ua = __float_as_uint(a);
    unsigned int ub = __float_as_uint(b);
    ua += 0x7fff + ((ua >> 16) & 1);
    ub += 0x7fff + ((ub >> 16) & 1);
    return (ua >> 16) | (ub & 0xffff0000u);
}
__device__ inline float2 bf2_to_f2(unsigned int u) {
    return make_float2(__uint_as_float(u << 16),
                       __uint_as_float(u & 0xffff0000u));
}

// LDS union: gemm path uses xs (32 KB); bin path uses b (25.3 KB).
union SMem {
    float xs[128 * 64];                   // 32 KB, [k][node]
    struct {
        unsigned int srt[EPB];            // 12.8 KB
        int hist[NBUCK];
        int base[NBUCK];
        int cur[NBUCK];
        int gbase[NBUCK];                 // 12.5 KB
        int wsum[4];
    } b;
};

// ---------------------------------------------------------------------------
// Fused kernel: blocks [0, GEMMB) run the x@W GEMM (+ logit epilogue, bf16
// pack); blocks [GEMMB, GEMMB+BINB) run edge bucket-binning. The two jobs
// are independent and have complementary pipe usage (FMA/LDS vs global
// atomics/latency) — co-residency turns t_g + t_b into ~max(t_g, t_b).
// cnt[] is zeroed by hipMemsetAsync before this dispatch (no intra-dispatch
// ordering assumptions).
// ---------------------------------------------------------------------------
__global__ __launch_bounds__(256) void k_fused(const float* __restrict__ x,
                                               const float* __restrict__ W,
                                               const float* __restrict__ att_s,
                                               const float* __restrict__ att_d,
                                               const int* __restrict__ ei,
                                               unsigned int* __restrict__ h_bf,
                                               float* __restrict__ asrc,
                                               float* __restrict__ adst,
                                               int* __restrict__ cnt,
                                               unsigned int* __restrict__ bin) {
    __shared__ SMem sm;
    const int tid = threadIdx.x;

    if (blockIdx.x < GEMMB) {
        // ------------------------- GEMM path -------------------------
        const int row0 = blockIdx.x * 64;

        for (int i = tid; i < 64 * 32; i += 256) {
            const int r = i & 63;
            const int k4 = i >> 6;
            const int row = row0 + r;
            float4 v = make_float4(0.f, 0.f, 0.f, 0.f);
            if (row < N_NODES) v = ((const float4*)x)[row * 32 + k4];
            float* d = sm.xs + (k4 * 4) * 64 + r;   // lane-consecutive writes
            d[0]   = v.x;
            d[64]  = v.y;
            d[128] = v.z;
            d[192] = v.w;
        }
        __syncthreads();

        const int colg = tid & 31;
        const int rowg = tid >> 5;
        float acc[8][4];
#pragma unroll
        for (int r = 0; r < 8; ++r)
#pragma unroll
            for (int j = 0; j < 4; ++j) acc[r][j] = 0.f;

#pragma unroll 4
        for (int k = 0; k < 128; ++k) {
            const float4 w = ((const float4*)W)[k * 32 + colg];
            const float* xr = sm.xs + k * 64 + rowg * 8;
            const float4 xa = *(const float4*)(xr);
            const float4 xb = *(const float4*)(xr + 4);
            const float xv[8] = {xa.x, xa.y, xa.z, xa.w, xb.x, xb.y, xb.z, xb.w};
            const float wv[4] = {w.x, w.y, w.z, w.w};
#pragma unroll
            for (int r = 0; r < 8; ++r)
#pragma unroll
                for (int j = 0; j < 4; ++j) acc[r][j] += xv[r] * wv[j];
        }

        const int hd = colg >> 2;
        const float4 asv = ((const float4*)att_s)[colg];
        const float4 adv = ((const float4*)att_d)[colg];
#pragma unroll
        for (int r = 0; r < 8; ++r) {
            const int row = row0 + rowg * 8 + r;
            float ps = acc[r][0] * asv.x + acc[r][1] * asv.y +
                       acc[r][2] * asv.z + acc[r][3] * asv.w;
            float pd = acc[r][0] * adv.x + acc[r][1] * adv.y +
                       acc[r][2] * adv.z + acc[r][3] * adv.w;
            ps += __shfl_xor(ps, 1); ps += __shfl_xor(ps, 2);
            pd += __shfl_xor(pd, 1); pd += __shfl_xor(pd, 2);
            if (row < N_NODES) {
                if ((colg & 3) == 0) {
                    asrc[row * 8 + hd] = ps * LOG2E;   // pre-scale for exp2
                    adst[row * 8 + hd] = pd * LOG2E;
                }
                uint2 p;
                p.x = f2_to_bf2(acc[r][0], acc[r][1]);
                p.y = f2_to_bf2(acc[r][2], acc[r][3]);
                ((uint2*)h_bf)[row * 32 + colg] = p;
            }
        }
    } else {
        // ------------------------- BIN path -------------------------
        const int e0 = (blockIdx.x - GEMMB) * EPB;
        const int lane = tid & 63;
        const int wid = tid >> 6;

        for (int b = tid; b < NBUCK; b += 256) sm.b.hist[b] = 0;
        __syncthreads();

        // pass 1: histogram (bucket = dst >> 6)
        for (int i = tid; i < EPB; i += 256)
            atomicAdd(&sm.b.hist[ei[N_EDGES + e0 + i] >> 6], 1);
        __syncthreads();

        // exclusive scan: thread owns buckets 4t..4t+3 (4*256 >= NBUCK),
        // two-level shfl scan of per-thread totals
        const int b4 = tid * 4;
        const int l0 = (b4     < NBUCK) ? sm.b.hist[b4]     : 0;
        const int l1 = (b4 + 1 < NBUCK) ? sm.b.hist[b4 + 1] : 0;
        const int l2 = (b4 + 2 < NBUCK) ? sm.b.hist[b4 + 2] : 0;
        const int l3 = (b4 + 3 < NBUCK) ? sm.b.hist[b4 + 3] : 0;
        const int tot = l0 + l1 + l2 + l3;
        int inc = tot;
#pragma unroll
        for (int off = 1; off < 64; off <<= 1) {
            const int u = __shfl_up(inc, off);
            if (lane >= off) inc += u;
        }
        if (lane == 63) sm.b.wsum[wid] = inc;
        __syncthreads();
        int run = inc - tot;
        for (int w2 = 0; w2 < wid; ++w2) run += sm.b.wsum[w2];
        if (b4     < NBUCK) { sm.b.base[b4]     = run; sm.b.cur[b4]     = run; } run += l0;
        if (b4 + 1 < NBUCK) { sm.b.base[b4 + 1] = run; sm.b.cur[b4 + 1] = run; } run += l1;
        if (b4 + 2 < NBUCK) { sm.b.base[b4 + 2] = run; sm.b.cur[b4 + 2] = run; } run += l2;
        if (b4 + 3 < NBUCK) { sm.b.base[b4 + 3] = run; sm.b.cur[b4 + 3] = run; }
        __syncthreads();

        // pass 2: scatter into sorted LDS
        for (int i = tid; i < EPB; i += 256) {
            const unsigned src = (unsigned)ei[e0 + i];
            const unsigned dst = (unsigned)ei[N_EDGES + e0 + i];
            const int p = atomicAdd(&sm.b.cur[dst >> 6], 1);
            if ((unsigned)p < (unsigned)EPB) sm.b.srt[p] = (dst << 16) | src;
        }
        __syncthreads();

        // reserve global ranges (one atomic per non-empty bucket)
        for (int b = tid; b < NBUCK; b += 256)
            sm.b.gbase[b] = (sm.b.hist[b] > 0) ? atomicAdd(&cnt[b], sm.b.hist[b]) : 0;
        __syncthreads();

        // contiguous run copy-out
        for (int p = tid; p < EPB; p += 256) {
            const unsigned rec = sm.b.srt[p];
            const int b = rec >> 22;
            if (b < NBUCK) {
                const int pos = sm.b.gbase[b] + (p - sm.b.base[b]);
                if ((unsigned)pos < (unsigned)BCAP)
                    bin[(size_t)b * BCAP + pos] = rec;
            }
        }
    }
}

// ---------------------------------------------------------------------------
// Aggregation. One block (8 waves) per 64-node bucket. Counting sort, then
// per-wave node processing. Dyadic batching: exact 16-batches (no clamps,
// full MLP) + one 8-batch + one 4-batch + <=3 singles — removes the ~43%
// Poisson-tail padding of fixed depth-16. Producer/consumer ex via shfl.
// ---------------------------------------------------------------------------
__global__ __launch_bounds__(512) void k_aggr(const unsigned int* __restrict__ h_bf,
                                              const unsigned int* __restrict__ bin,
                                              const int* __restrict__ cnt,
                                              const float* __restrict__ asrc,
                                              const float* __restrict__ adst,
                                              const float* __restrict__ bias,
                                              float* __restrict__ out) {
    __shared__ unsigned int srt[BCAP];    // 5.2 KB
    __shared__ int hist[BNODES], base[BNODES], scn[BNODES];

    const int bkt = blockIdx.x;
    const int tid = threadIdx.x;
    const int wid = tid >> 6;
    const int lane = tid & 63;
    const int hd = lane >> 3;     // consumer head (channels lane*2, lane*2+1)
    const int eslot = lane >> 3;  // producer edge slot 0..7
    const int phead = lane & 7;   // producer head

    const int cntb = min(cnt[bkt], BCAP);
    const unsigned int* seg = bin + (size_t)bkt * BCAP;

    if (tid < BNODES) hist[tid] = 0;
    __syncthreads();

    // single pass: read seg once, rank via LDS atomic, keep in registers
    unsigned int myrec[3];
    int myrank[3];
    int nrec = 0;
    for (int i = tid; i < cntb; i += 512) {
        const unsigned rec = seg[i];
        myrank[nrec] = atomicAdd(&hist[(rec >> 16) & 63], 1);
        myrec[nrec] = rec;
        ++nrec;
    }
    __syncthreads();

    if (tid < BNODES) scn[tid] = hist[tid];
    __syncthreads();
    for (int off = 1; off < BNODES; off <<= 1) {
        int v = 0;
        if (tid < BNODES && tid >= off) v = scn[tid - off];
        __syncthreads();
        if (tid < BNODES) scn[tid] += v;
        __syncthreads();
    }
    if (tid < BNODES) base[tid] = scn[tid] - hist[tid];
    __syncthreads();

    for (int k = 0; k < nrec; ++k) {
        const unsigned rec = myrec[k];
        const int p = base[(rec >> 16) & 63] + myrank[k];
        if ((unsigned)p < (unsigned)BCAP) srt[p] = rec;
    }
    __syncthreads();

    // per-wave node processing: wave wid handles dlocal = wid, wid+8, ...
    for (int dl = wid; dl < BNODES; dl += 8) {
        const int d = bkt * BNODES + dl;
        if (d >= N_NODES) continue;
        const int jb = base[dl];
        const int jn = hist[dl];

        const float adst_h = adst[d * 8 + hd];      // consumer head
        const float adst_p = adst[d * 8 + phead];   // producer head
        const float asrc_self = asrc[d * 8 + hd];
        const float2 hdv = bf2_to_f2(h_bf[d * 64 + lane]);

        float es = asrc_self + adst_h;
        es = fmaxf(es, NEG_SLOPE * es);       // LeakyReLU, slope<1
        const float exs = exp2f(es);          // logits pre-scaled by log2e

        float2 acc = make_float2(0.f, 0.f);
        float den = 0.f;

        int j0 = 0;
        // exact 16-batches: no clamping, no masking
        for (; j0 + 16 <= jn; j0 += 16) {
            int s[16];
#pragma unroll
            for (int i = 0; i < 16; ++i)
                s[i] = (int)(srt[jb + j0 + i] & 0xffffu);
            unsigned int hv[16];
#pragma unroll
            for (int i = 0; i < 16; ++i) hv[i] = h_bf[s[i] * 64 + lane];

            const int sa = (int)(srt[jb + j0 + eslot] & 0xffffu);
            const int sb = (int)(srt[jb + j0 + eslot + 8] & 0xffffu);
            float eA = asrc[sa * 8 + phead] + adst_p;
            float eB = asrc[sb * 8 + phead] + adst_p;
            eA = fmaxf(eA, NEG_SLOPE * eA);
            eB = fmaxf(eB, NEG_SLOPE * eB);
            const float exA = exp2f(eA);
            const float exB = exp2f(eB);

#pragma unroll
            for (int i = 0; i < 16; ++i) {
                const float ex = __shfl((i < 8) ? exA : exB,
                                        ((i & 7) << 3) | hd, 64);
                const float2 hv2 = bf2_to_f2(hv[i]);
                acc.x += ex * hv2.x;
                acc.y += ex * hv2.y;
                den += ex;
            }
        }
        // one exact 8-batch
        if (jn - j0 >= 8) {
            int s[8];
#pragma unroll
            for (int i = 0; i < 8; ++i)
                s[i] = (int)(srt[jb + j0 + i] & 0xffffu);
            unsigned int hv[8];
#pragma unroll
            for (int i = 0; i < 8; ++i) hv[i] = h_bf[s[i] * 64 + lane];

            const int sa = (int)(srt[jb + j0 + eslot] & 0xffffu);
            float eA = asrc[sa * 8 + phead] + adst_p;
            eA = fmaxf(eA, NEG_SLOPE * eA);
            const float exA = exp2f(eA);
#pragma unroll
            for (int i = 0; i < 8; ++i) {
                const float ex = __shfl(exA, (i << 3) | hd, 64);
                const float2 hv2 = bf2_to_f2(hv[i]);
                acc.x += ex * hv2.x;
                acc.y += ex * hv2.y;
                den += ex;
            }
            j0 += 8;
        }
        // one exact 4-batch (producers duplicated across eslot&3)
        if (jn - j0 >= 4) {
            int s[4];
#pragma unroll
            for (int i = 0; i < 4; ++i)
                s[i] = (int)(srt[jb + j0 + i] & 0xffffu);
            unsigned int hv[4];
#pragma unroll
            for (int i = 0; i < 4; ++i) hv[i] = h_bf[s[i] * 64 + lane];

            const int sa = (int)(srt[jb + j0 + (eslot & 3)] & 0xffffu);
            float eA = asrc[sa * 8 + phead] + adst_p;
            eA = fmaxf(eA, NEG_SLOPE * eA);
            const float exA = exp2f(eA);
#pragma unroll
            for (int i = 0; i < 4; ++i) {
                const float ex = __shfl(exA, (i << 3) | hd, 64);
                const float2 hv2 = bf2_to_f2(hv[i]);
                acc.x += ex * hv2.x;
                acc.y += ex * hv2.y;
                den += ex;
            }
            j0 += 4;
        }
        // <=3 singles
        for (; j0 < jn; ++j0) {
            const int s = (int)(srt[jb + j0] & 0xffffu);
            const unsigned int hvv = h_bf[s * 64 + lane];
            float e = asrc[s * 8 + hd] + adst_h;
            e = fmaxf(e, NEG_SLOPE * e);
            const float ex = exp2f(e);
            const float2 hv2 = bf2_to_f2(hvv);
            acc.x += ex * hv2.x;
            acc.y += ex * hv2.y;
            den += ex;
        }

        const float dtot = den + exs + EPS;
        const float2 b2 = ((const float2*)bias)[lane];
        float vx = (acc.x + exs * hdv.x) / dtot + b2.x;
        float vy = (acc.y + exs * hdv.y) / dtot + b2.y;
        vx = (vx > 0.f) ? vx : expm1f(vx);
        vy = (vy > 0.f) ? vy : expm1f(vy);
        ((float2*)out)[d * 64 + lane] = make_float2(vx, vy);
    }
}

extern "C" void kernel_launch(void* const* d_in, const int* in_sizes, int n_in,
                              void* d_out, int out_size, void* d_ws, size_t ws_size,
                              hipStream_t stream) {
    const float* x     = (const float*)d_in[0];
    const int*   ei    = (const int*)d_in[1];
    const float* W     = (const float*)d_in[2];
    const float* att_s = (const float*)d_in[3];
    const float* att_d = (const float*)d_in[4];
    const float* bias  = (const float*)d_in[5];
    float* out = (float*)d_out;

    // workspace layout (~20.2 MB)
    unsigned int* h_bf = (unsigned int*)d_ws;                   // 12.8 MB
    float* asrc = (float*)(h_bf + (size_t)N_NODES * 64);        // 1.6 MB
    float* adst = asrc + (size_t)N_NODES * HEADS;               // 1.6 MB
    unsigned int* bin = (unsigned int*)(adst + (size_t)N_NODES * HEADS); // 4.1 MB
    int* cnt = (int*)(bin + (size_t)NBUCK * BCAP);              // 782 ints

    hipMemsetAsync(cnt, 0, NBUCK * sizeof(int), stream);
    k_fused<<<GEMMB + BINB, 256, 0, stream>>>(x, W, att_s, att_d, ei,
                                              h_bf, asrc, adst, cnt, bin);
    k_aggr<<<NBUCK, 512, 0, stream>>>(h_bf, bin, cnt, asrc, adst, bias, out);
}

// Round 5
// 174.294 us; speedup vs baseline: 1.0098x; 1.0098x over previous
//
#include <hip/hip_runtime.h>

#define N_NODES 50000
#define N_EDGES 800000
#define HEADS 8
#define NEG_SLOPE 0.2f
#define EPS 1e-16f
#define NBUCK 782            // ceil(50000/64) buckets of 64 dst nodes
#define BNODES 64
#define BCAP 1312            // bucket capacity (load ~Poisson(1023); +9 sigma)
#define GEMMB 782            // gemm blocks (64 rows each)
#define BINB 250             // bin blocks
#define EPB 3200             // 800000 / 250 edges per bin block
#define LOG2E 1.4426950408889634f

// bf16x2 pack/unpack (RNE), exact unpack
__device__ inline unsigned int f2_to_bf2(float a, float b) {
    unsigned int ua = __float_as_uint(a);
    unsigned int ub = __float_as_uint(b);
    ua += 0x7fff + ((ua >> 16) & 1);
    ub += 0x7fff + ((ub >> 16) & 1);
    return (ua >> 16) | (ub & 0xffff0000u);
}
__device__ inline float2 bf2_to_f2(unsigned int u) {
    return make_float2(__uint_as_float(u << 16),
                       __uint_as_float(u & 0xffff0000u));
}

// LDS union: gemm path uses xs (32 KB); bin path uses b (25.3 KB).
union SMem {
    float xs[128 * 64];                   // 32 KB, [k][node]
    struct {
        unsigned int srt[EPB];            // 12.8 KB
        int hist[NBUCK];
        int base[NBUCK];
        int cur[NBUCK];
        int gbase[NBUCK];                 // 12.5 KB
        int wsum[4];
    } b;
};

// ---------------------------------------------------------------------------
// Fused kernel: blocks [0, GEMMB) run the x@W GEMM (+ logit epilogue, bf16
// pack); blocks [GEMMB, GEMMB+BINB) run edge bucket-binning.
// GEMM k-loop uses an explicit register double-buffer on the W loads
// (VGPR 48 in r4 proved the compiler wasn't pipelining: load-wait-FMA
// exposed ~250cy L2 latency every 4 k-steps at 2 waves/SIMD).
// ---------------------------------------------------------------------------
__global__ __launch_bounds__(256) void k_fused(const float* __restrict__ x,
                                               const float* __restrict__ W,
                                               const float* __restrict__ att_s,
                                               const float* __restrict__ att_d,
                                               const int* __restrict__ ei,
                                               unsigned int* __restrict__ h_bf,
                                               float* __restrict__ asrc,
                                               float* __restrict__ adst,
                                               int* __restrict__ cnt,
                                               unsigned int* __restrict__ bin) {
    __shared__ SMem sm;
    const int tid = threadIdx.x;

    if (blockIdx.x < GEMMB) {
        // ------------------------- GEMM path -------------------------
        const int row0 = blockIdx.x * 64;

        for (int i = tid; i < 64 * 32; i += 256) {
            const int r = i & 63;
            const int k4 = i >> 6;
            const int row = row0 + r;
            float4 v = make_float4(0.f, 0.f, 0.f, 0.f);
            if (row < N_NODES) v = ((const float4*)x)[row * 32 + k4];
            float* d = sm.xs + (k4 * 4) * 64 + r;   // lane-consecutive writes
            d[0]   = v.x;
            d[64]  = v.y;
            d[128] = v.z;
            d[192] = v.w;
        }
        __syncthreads();

        const int colg = tid & 31;
        const int rowg = tid >> 5;
        float acc[8][4];
#pragma unroll
        for (int r = 0; r < 8; ++r)
#pragma unroll
            for (int j = 0; j < 4; ++j) acc[r][j] = 0.f;

        // W pointer for this thread's 4 columns; stride 32 float4 per k.
        const float4* Wp = ((const float4*)W) + colg;
        // software pipeline: W for group k+4 loads during group k's FMAs
        float4 w0 = Wp[0], w1 = Wp[32], w2 = Wp[64], w3 = Wp[96];

        for (int k = 0; k < 128; k += 4) {
            const int kn = (k + 4) & 127;           // wraps on last iter (dead)
            float4 n0 = Wp[kn * 32];
            float4 n1 = Wp[kn * 32 + 32];
            float4 n2 = Wp[kn * 32 + 64];
            float4 n3 = Wp[kn * 32 + 96];

#pragma unroll
            for (int kk = 0; kk < 4; ++kk) {
                const float4 w = (kk == 0) ? w0 : (kk == 1) ? w1
                               : (kk == 2) ? w2 : w3;
                const float* xr = sm.xs + (k + kk) * 64 + rowg * 8;
                const float4 xa = *(const float4*)(xr);
                const float4 xb = *(const float4*)(xr + 4);
                const float xv[8] = {xa.x, xa.y, xa.z, xa.w,
                                     xb.x, xb.y, xb.z, xb.w};
                const float wv[4] = {w.x, w.y, w.z, w.w};
#pragma unroll
                for (int r = 0; r < 8; ++r)
#pragma unroll
                    for (int j = 0; j < 4; ++j) acc[r][j] += xv[r] * wv[j];
            }
            w0 = n0; w1 = n1; w2 = n2; w3 = n3;
        }

        const int hd = colg >> 2;
        const float4 asv = ((const float4*)att_s)[colg];
        const float4 adv = ((const float4*)att_d)[colg];
#pragma unroll
        for (int r = 0; r < 8; ++r) {
            const int row = row0 + rowg * 8 + r;
            float ps = acc[r][0] * asv.x + acc[r][1] * asv.y +
                       acc[r][2] * asv.z + acc[r][3] * asv.w;
            float pd = acc[r][0] * adv.x + acc[r][1] * adv.y +
                       acc[r][2] * adv.z + acc[r][3] * adv.w;
            ps += __shfl_xor(ps, 1); ps += __shfl_xor(ps, 2);
            pd += __shfl_xor(pd, 1); pd += __shfl_xor(pd, 2);
            if (row < N_NODES) {
                if ((colg & 3) == 0) {
                    asrc[row * 8 + hd] = ps * LOG2E;   // pre-scale for exp2
                    adst[row * 8 + hd] = pd * LOG2E;
                }
                uint2 p;
                p.x = f2_to_bf2(acc[r][0], acc[r][1]);
                p.y = f2_to_bf2(acc[r][2], acc[r][3]);
                ((uint2*)h_bf)[row * 32 + colg] = p;
            }
        }
    } else {
        // ------------------------- BIN path -------------------------
        const int e0 = (blockIdx.x - GEMMB) * EPB;
        const int lane = tid & 63;
        const int wid = tid >> 6;

        for (int b = tid; b < NBUCK; b += 256) sm.b.hist[b] = 0;
        __syncthreads();

        // pass 1: histogram (bucket = dst >> 6)
        for (int i = tid; i < EPB; i += 256)
            atomicAdd(&sm.b.hist[ei[N_EDGES + e0 + i] >> 6], 1);
        __syncthreads();

        // exclusive scan: thread owns buckets 4t..4t+3 (4*256 >= NBUCK),
        // two-level shfl scan of per-thread totals
        const int b4 = tid * 4;
        const int l0 = (b4     < NBUCK) ? sm.b.hist[b4]     : 0;
        const int l1 = (b4 + 1 < NBUCK) ? sm.b.hist[b4 + 1] : 0;
        const int l2 = (b4 + 2 < NBUCK) ? sm.b.hist[b4 + 2] : 0;
        const int l3 = (b4 + 3 < NBUCK) ? sm.b.hist[b4 + 3] : 0;
        const int tot = l0 + l1 + l2 + l3;
        int inc = tot;
#pragma unroll
        for (int off = 1; off < 64; off <<= 1) {
            const int u = __shfl_up(inc, off);
            if (lane >= off) inc += u;
        }
        if (lane == 63) sm.b.wsum[wid] = inc;
        __syncthreads();
        int run = inc - tot;
        for (int w2 = 0; w2 < wid; ++w2) run += sm.b.wsum[w2];
        if (b4     < NBUCK) { sm.b.base[b4]     = run; sm.b.cur[b4]     = run; } run += l0;
        if (b4 + 1 < NBUCK) { sm.b.base[b4 + 1] = run; sm.b.cur[b4 + 1] = run; } run += l1;
        if (b4 + 2 < NBUCK) { sm.b.base[b4 + 2] = run; sm.b.cur[b4 + 2] = run; } run += l2;
        if (b4 + 3 < NBUCK) { sm.b.base[b4 + 3] = run; sm.b.cur[b4 + 3] = run; }
        __syncthreads();

        // pass 2: scatter into sorted LDS
        for (int i = tid; i < EPB; i += 256) {
            const unsigned src = (unsigned)ei[e0 + i];
            const unsigned dst = (unsigned)ei[N_EDGES + e0 + i];
            const int p = atomicAdd(&sm.b.cur[dst >> 6], 1);
            if ((unsigned)p < (unsigned)EPB) sm.b.srt[p] = (dst << 16) | src;
        }
        __syncthreads();

        // reserve global ranges (one atomic per non-empty bucket)
        for (int b = tid; b < NBUCK; b += 256)
            sm.b.gbase[b] = (sm.b.hist[b] > 0) ? atomicAdd(&cnt[b], sm.b.hist[b]) : 0;
        __syncthreads();

        // contiguous run copy-out
        for (int p = tid; p < EPB; p += 256) {
            const unsigned rec = sm.b.srt[p];
            const int b = rec >> 22;
            if (b < NBUCK) {
                const int pos = sm.b.gbase[b] + (p - sm.b.base[b]);
                if ((unsigned)pos < (unsigned)BCAP)
                    bin[(size_t)b * BCAP + pos] = rec;
            }
        }
    }
}

// ---------------------------------------------------------------------------
// Aggregation (round-3 structure, proven 52.8 us profiled; the dyadic-tail
// variant regressed to 56.5 by breaking the hot-loop schedule). One block
// (8 waves) per bucket; counting sort; uniform clamped depth-16 batches;
// producer/consumer ex via shfl.
// ---------------------------------------------------------------------------
__global__ __launch_bounds__(512) void k_aggr(const unsigned int* __restrict__ h_bf,
                                              const unsigned int* __restrict__ bin,
                                              const int* __restrict__ cnt,
                                              const float* __restrict__ asrc,
                                              const float* __restrict__ adst,
                                              const float* __restrict__ bias,
                                              float* __restrict__ out) {
    __shared__ unsigned int srt[BCAP];    // 5.2 KB
    __shared__ int hist[BNODES], base[BNODES], scn[BNODES];

    const int bkt = blockIdx.x;
    const int tid = threadIdx.x;
    const int wid = tid >> 6;
    const int lane = tid & 63;
    const int hd = lane >> 3;     // consumer head (channels lane*2, lane*2+1)
    const int eslot = lane >> 3;  // producer edge slot 0..7
    const int phead = lane & 7;   // producer head

    const int cntb = min(cnt[bkt], BCAP);
    const unsigned int* seg = bin + (size_t)bkt * BCAP;

    if (tid < BNODES) hist[tid] = 0;
    __syncthreads();

    // single pass: read seg once, rank via LDS atomic, keep in registers
    unsigned int myrec[3];
    int myrank[3];
    int nrec = 0;
    for (int i = tid; i < cntb; i += 512) {
        const unsigned rec = seg[i];
        myrank[nrec] = atomicAdd(&hist[(rec >> 16) & 63], 1);
        myrec[nrec] = rec;
        ++nrec;
    }
    __syncthreads();

    if (tid < BNODES) scn[tid] = hist[tid];
    __syncthreads();
    for (int off = 1; off < BNODES; off <<= 1) {
        int v = 0;
        if (tid < BNODES && tid >= off) v = scn[tid - off];
        __syncthreads();
        if (tid < BNODES) scn[tid] += v;
        __syncthreads();
    }
    if (tid < BNODES) base[tid] = scn[tid] - hist[tid];
    __syncthreads();

    for (int k = 0; k < nrec; ++k) {
        const unsigned rec = myrec[k];
        const int p = base[(rec >> 16) & 63] + myrank[k];
        if ((unsigned)p < (unsigned)BCAP) srt[p] = rec;
    }
    __syncthreads();

    // per-wave node processing: wave wid handles dlocal = wid, wid+8, ...
    for (int dl = wid; dl < BNODES; dl += 8) {
        const int d = bkt * BNODES + dl;
        if (d >= N_NODES) continue;
        const int jb = base[dl];
        const int jn = hist[dl];

        const float adst_h = adst[d * 8 + hd];      // consumer head
        const float adst_p = adst[d * 8 + phead];   // producer head
        const float asrc_self = asrc[d * 8 + hd];
        const float2 hdv = bf2_to_f2(h_bf[d * 64 + lane]);

        float es = asrc_self + adst_h;
        es = fmaxf(es, NEG_SLOPE * es);       // LeakyReLU, slope<1
        const float exs = exp2f(es);          // logits pre-scaled by log2e

        float2 acc = make_float2(0.f, 0.f);
        float den = 0.f;

        for (int j0 = 0; j0 < jn; j0 += 16) {
            // broadcast copies of the 16 src ids (same addr across wave: free)
            int s[16];
#pragma unroll
            for (int i = 0; i < 16; ++i) {
                const int jj = j0 + i;
                s[i] = (int)(srt[jb + ((jj < jn) ? jj : jn - 1)] & 0xffffu);
            }
            // issue all 16 row-gathers early (MLP)
            unsigned int hv[16];
#pragma unroll
            for (int i = 0; i < 16; ++i) hv[i] = h_bf[s[i] * 64 + lane];

            // producer lanes: ex for (edge eslot / eslot+8, head phead)
            const int ia = j0 + eslot;
            const int ib = ia + 8;
            const int sa = (int)(srt[jb + min(ia, jn - 1)] & 0xffffu);
            const int sb = (int)(srt[jb + min(ib, jn - 1)] & 0xffffu);
            float eA = asrc[sa * 8 + phead] + adst_p;
            float eB = asrc[sb * 8 + phead] + adst_p;
            eA = fmaxf(eA, NEG_SLOPE * eA);
            eB = fmaxf(eB, NEG_SLOPE * eB);
            const float exA = (ia < jn) ? exp2f(eA) : 0.f;
            const float exB = (ib < jn) ? exp2f(eB) : 0.f;

#pragma unroll
            for (int i = 0; i < 16; ++i) {
                // producer of (edge i, head hd) is lane ((i&7)<<3) | hd
                const float ex = __shfl((i < 8) ? exA : exB,
                                        ((i & 7) << 3) | hd, 64);
                const float2 hv2 = bf2_to_f2(hv[i]);
                acc.x += ex * hv2.x;
                acc.y += ex * hv2.y;
                den += ex;
            }
        }

        const float dtot = den + exs + EPS;
        const float2 b2 = ((const float2*)bias)[lane];
        float vx = (acc.x + exs * hdv.x) / dtot + b2.x;
        float vy = (acc.y + exs * hdv.y) / dtot + b2.y;
        vx = (vx > 0.f) ? vx : expm1f(vx);
        vy = (vy > 0.f) ? vy : expm1f(vy);
        ((float2*)out)[d * 64 + lane] = make_float2(vx, vy);
    }
}

extern "C" void kernel_launch(void* const* d_in, const int* in_sizes, int n_in,
                              void* d_out, int out_size, void* d_ws, size_t ws_size,
                              hipStream_t stream) {
    const float* x     = (const float*)d_in[0];
    const int*   ei    = (const int*)d_in[1];
    const float* W     = (const float*)d_in[2];
    const float* att_s = (const float*)d_in[3];
    const float* att_d = (const float*)d_in[4];
    const float* bias  = (const float*)d_in[5];
    float* out = (float*)d_out;

    // workspace layout (~20.2 MB)
    unsigned int* h_bf = (unsigned int*)d_ws;                   // 12.8 MB
    float* asrc = (float*)(h_bf + (size_t)N_NODES * 64);        // 1.6 MB
    float* adst = asrc + (size_t)N_NODES * HEADS;               // 1.6 MB
    unsigned int* bin = (unsigned int*)(adst + (size_t)N_NODES * HEADS); // 4.1 MB
    int* cnt = (int*)(bin + (size_t)NBUCK * BCAP);              // 782 ints

    hipMemsetAsync(cnt, 0, NBUCK * sizeof(int), stream);
    k_fused<<<GEMMB + BINB, 256, 0, stream>>>(x, W, att_s, att_d, ei,
                                              h_bf, asrc, adst, cnt, bin);
    k_aggr<<<NBUCK, 512, 0, stream>>>(h_bf, bin, cnt, asrc, adst, bias, out);
}